// Round 2
// baseline (679.841 us; speedup 1.0000x reference)
//
#include <hip/hip_runtime.h>
#include <hip/hip_bf16.h>

// PartialSum: x[B=2048, P=1024 * L=64] fp32 -> out[B, P] = per-64-element sum.
//
// Memory-bound streaming reduction (512 MiB read, 8 MiB write, ~87 us floor
// at 6.3 TB/s achievable). R2 change: persistent grid-stride kernel instead
// of 131072 one-shot workgroups — 8192 blocks, each thread handles 16 float4
// via 4 outer iterations x 4-way unroll, so every thread keeps 4 independent
// global loads in flight (vmcnt pipelining) and WG dispatch overhead drops
// 16x. Load pattern stays fully lane-contiguous: lane i of a wave reads
// base + i*16B -> 1 KiB per wave instruction.

__device__ __forceinline__ float reduce16(float s) {
    // Sum across the 16 lanes sharing one partition (lanes p*16..p*16+15).
    s += __shfl_xor(s, 1, 64);
    s += __shfl_xor(s, 2, 64);
    s += __shfl_xor(s, 4, 64);
    s += __shfl_xor(s, 8, 64);
    return s;
}

__global__ __launch_bounds__(256) void PartialSum_85478439125876_kernel(
    const float4* __restrict__ x4, float* __restrict__ out, long long n4) {
    const long long stride = (long long)gridDim.x * blockDim.x;
    long long i = (long long)blockIdx.x * blockDim.x + threadIdx.x;
    const bool writer = (threadIdx.x & 15) == 0;

    // Main loop: 4 independent loads per iteration for memory-level
    // parallelism; reductions/stores overlap with the next loads.
    for (; i + 3 * stride < n4; i += 4 * stride) {
        float4 a = x4[i];
        float4 b = x4[i + stride];
        float4 c = x4[i + 2 * stride];
        float4 d = x4[i + 3 * stride];

        float sa = (a.x + a.y) + (a.z + a.w);
        float sb = (b.x + b.y) + (b.z + b.w);
        float sc = (c.x + c.y) + (c.z + c.w);
        float sd = (d.x + d.y) + (d.z + d.w);

        sa = reduce16(sa);
        sb = reduce16(sb);
        sc = reduce16(sc);
        sd = reduce16(sd);

        if (writer) {
            out[i >> 4] = sa;
            out[(i + stride) >> 4] = sb;
            out[(i + 2 * stride) >> 4] = sc;
            out[(i + 3 * stride) >> 4] = sd;
        }
    }
    // Tail (not taken for the bench shape: n4 = 2^25, 4*stride = 2^23).
    for (; i < n4; i += stride) {
        float4 a = x4[i];
        float s = reduce16((a.x + a.y) + (a.z + a.w));
        if (writer) out[i >> 4] = s;
    }
}

extern "C" void kernel_launch(void* const* d_in, const int* in_sizes, int n_in,
                              void* d_out, int out_size, void* d_ws, size_t ws_size,
                              hipStream_t stream) {
    const float* x = (const float*)d_in[0];
    float* out = (float*)d_out;

    long long n = (long long)in_sizes[0];   // 2048 * 65536 = 2^27
    long long n4 = n / 4;                   // 2^25 float4

    const int BLOCK = 256;
    const int GRID = 8192;  // 32 blocks/CU nominal; 16 float4/thread

    PartialSum_85478439125876_kernel<<<GRID, BLOCK, 0, stream>>>(
        (const float4*)x, out, n4);
}

// Round 3
// 672.094 us; speedup vs baseline: 1.0115x; 1.0115x over previous
//
#include <hip/hip_runtime.h>
#include <hip/hip_bf16.h>
#include <stdint.h>

// PartialSum: x[2048, 1024*64] fp32 -> out[2048,1024] = per-64-float sum.
// Memory-bound: 512 MiB read + 8 MiB write; ~87 us floor at 6.3 TB/s.
//
// R3: canonical LDS-staged structure, shuffle-free.
//  - 8192 one-shot blocks x 256 threads; block owns 256 partitions = 64 KiB
//    contiguous input, 64 KiB LDS (2 blocks/CU of the 160 KiB).
//  - Phase 1: 16 x global_load_lds(16B) passes. Each wave stages 1 KiB
//    contiguous (wave-uniform LDS base + lane*16 — the m104/m108 layout
//    constraint), no VGPR round-trip, all 16 DMAs in flight before the
//    single barrier.
//  - Phase 2: thread tid sums partition tid: 16 ds_read_b128 with XOR'd
//    q-order (q ^ (tid&7)) so each instruction spreads lanes evenly over
//    the 8 bank-quads (b128 minimum, no extra conflicts); 4 independent
//    float4 accumulators.
//  - Store: out[block*256 + tid] -> 1 KiB contiguous per block.

#define BLOCK 256
#define F4_PER_BLOCK 4096  // 256 partitions * 16 float4 = 64 KiB

typedef const __attribute__((address_space(1))) uint32_t glb_u32;
typedef __attribute__((address_space(3))) uint32_t lds_u32;

__global__ __launch_bounds__(BLOCK, 2) void PartialSum_85478439125876_kernel(
    const float* __restrict__ x, float* __restrict__ out) {
    __shared__ float4 smem[F4_PER_BLOCK];

    const int tid = threadIdx.x;
    const int wave = tid >> 6;
    const int lane = tid & 63;

    const float* gbase = x + (size_t)blockIdx.x * (F4_PER_BLOCK * 4);

    // ---- Phase 1: stage 64 KiB global -> LDS, 16 async 1-KiB/wave passes.
#pragma unroll
    for (int t = 0; t < 16; ++t) {
        const int f4 = t * 256 + wave * 64 + lane;           // per-lane global float4 idx
        glb_u32* g = (glb_u32*)(gbase + (size_t)f4 * 4);
        // wave-uniform LDS base (float4 units); HW adds lane*16.
        lds_u32* l = (lds_u32*)(smem + (t * 256 + wave * 64));
        __builtin_amdgcn_global_load_lds(g, l, 16, 0, 0);
    }

    __syncthreads();  // drains vmcnt -> all staged data visible

    // ---- Phase 2: thread tid reduces partition tid (16 float4 in LDS).
    const float4* s4 = (const float4*)smem;
    const int base = tid * 16;
    const int sw = tid & 7;  // XOR swizzle: spread lanes across bank-quads

    float4 a0 = s4[base + (0 ^ sw)];
    float4 a1 = s4[base + (1 ^ sw)];
    float4 a2 = s4[base + (2 ^ sw)];
    float4 a3 = s4[base + (3 ^ sw)];
#pragma unroll
    for (int q = 4; q < 16; q += 4) {
        float4 v0 = s4[base + ((q + 0) ^ sw)];
        float4 v1 = s4[base + ((q + 1) ^ sw)];
        float4 v2 = s4[base + ((q + 2) ^ sw)];
        float4 v3 = s4[base + ((q + 3) ^ sw)];
        a0.x += v0.x; a0.y += v0.y; a0.z += v0.z; a0.w += v0.w;
        a1.x += v1.x; a1.y += v1.y; a1.z += v1.z; a1.w += v1.w;
        a2.x += v2.x; a2.y += v2.y; a2.z += v2.z; a2.w += v2.w;
        a3.x += v3.x; a3.y += v3.y; a3.z += v3.z; a3.w += v3.w;
    }
    a0.x += a1.x; a0.y += a1.y; a0.z += a1.z; a0.w += a1.w;
    a2.x += a3.x; a2.y += a3.y; a2.z += a3.z; a2.w += a3.w;
    a0.x += a2.x; a0.y += a2.y; a0.z += a2.z; a0.w += a2.w;
    float s = (a0.x + a0.y) + (a0.z + a0.w);

    out[(size_t)blockIdx.x * BLOCK + tid] = s;  // 1 KiB contiguous per block
}

extern "C" void kernel_launch(void* const* d_in, const int* in_sizes, int n_in,
                              void* d_out, int out_size, void* d_ws, size_t ws_size,
                              hipStream_t stream) {
    const float* x = (const float*)d_in[0];
    float* out = (float*)d_out;

    long long n = (long long)in_sizes[0];       // 2048 * 65536 = 2^27 floats
    long long blocks = n / (F4_PER_BLOCK * 4);  // 8192

    PartialSum_85478439125876_kernel<<<(unsigned)blocks, BLOCK, 0, stream>>>(x, out);
}